// Round 10
// baseline (588.268 us; speedup 1.0000x reference)
//
#include <hip/hip_runtime.h>
#include <hip/hip_cooperative_groups.h>
#include <hip/hip_bf16.h>
#include <cstdint>

namespace cg = cooperative_groups;

#define SEQ 192
#define GRID 512

typedef float f32x4 __attribute__((ext_vector_type(4)));
typedef float f32x8 __attribute__((ext_vector_type(8)));
typedef __bf16 bf16;
typedef __bf16 bf16x8 __attribute__((ext_vector_type(8)));
typedef __bf16 bf16x4 __attribute__((ext_vector_type(4)));

#define MFMA_BF16(a, b, c) __builtin_amdgcn_mfma_f32_16x16x32_bf16(a, b, c, 0, 0, 0)

__device__ __forceinline__ bf16x8 cvt8(f32x8 v) {
  bf16x8 o;
#pragma unroll
  for (int i = 0; i < 8; i++) o[i] = (bf16)v[i];
  return o;
}

struct P {
  const float *x, *ln_w, *ln_b, *Wab, *b_ab, *WK, *WV, *Wout, *b_out;
  float *out, *proj, *ecum, *Zpart, *Lsum;
  bf16 *xn, *WVt2, *a, *c, *d, *eT, *bsum, *s1, *s2, *tTt, *ew;
};

// ---------- LDS-free bf16 GEMM core (C = A @ Bt^T). MODE1: bf16 row-major; MODE2: s2 layout ----------
template <int MODE>
__device__ __forceinline__ void gemm_body(const bf16* __restrict__ A, const bf16* __restrict__ Bt,
                                          bf16* __restrict__ C1, int N, int K, int nb, int mb,
                                          int tid) {
  int n0 = nb * 64, m0 = mb * 64;
  int wave = tid >> 6, lane = tid & 63;
  int lq = lane >> 4, l16 = lane & 15;
  const bf16* Ap = A + (size_t)(m0 + wave * 16 + l16) * K;
  f32x4 acc[4];
#pragma unroll
  for (int nt = 0; nt < 4; nt++) acc[nt] = (f32x4){0.f, 0.f, 0.f, 0.f};
  for (int k0 = 0; k0 < K; k0 += 32) {
    bf16x8 af = *(const bf16x8*)(Ap + k0 + lq * 8);
#pragma unroll
    for (int nt = 0; nt < 4; nt++) {
      bf16x8 bv = *(const bf16x8*)(Bt + (size_t)(n0 + nt * 16 + l16) * K + k0 + lq * 8);
      acc[nt] = MFMA_BF16(af, bv, acc[nt]);
    }
  }
  int cm = m0 + wave * 16 + lq * 4;
#pragma unroll
  for (int nt = 0; nt < 4; nt++) {
    int n = n0 + nt * 16 + l16;
    if constexpr (MODE == 1) {
#pragma unroll
      for (int rg = 0; rg < 4; rg++) C1[(size_t)(cm + rg) * N + n] = (bf16)acc[nt][rg];
    } else {
      int r = cm >> 6, i0 = cm & 63;
      bf16x4 pk = {(bf16)acc[nt][0], (bf16)acc[nt][1], (bf16)acc[nt][2], (bf16)acc[nt][3]};
      *(bf16x4*)(C1 + (size_t)r * 12288 + (size_t)n * 64 + i0) = pk;
    }
  }
}

// ---------- P1: WVt2 transpose (u<512) + LayerNorm (u 512..703) ----------
__device__ __forceinline__ void ph1(const P& p, char* sm, int u, int tid) {
  if (u < 512) {
    int g = u & 63, hh = u >> 6;
    float* ld = (float*)sm;  // 64x65 f32
    int f = tid & 63, r4 = tid >> 6;
#pragma unroll
    for (int it = 0; it < 16; it++) {
      int hp = it * 4 + r4;
      ld[hp * 65 + f] = p.WV[(((size_t)(hh * 64 + hp) * 64 + g) * 64) + f];
    }
    __syncthreads();
    int hp2 = tid & 63;
#pragma unroll
    for (int it = 0; it < 16; it++) {
      int ff = it * 4 + r4;
      p.WVt2[(size_t)hh * 262144 + (size_t)(ff * 64 + g) * 64 + hp2] = (bf16)ld[hp2 * 65 + ff];
    }
    __syncthreads();
  } else {
    int r = u - 512;
    const float* xr = p.x + (size_t)r * 512;
    float v0 = xr[tid], v1 = xr[tid + 256];
    float s = v0 + v1, s2 = v0 * v0 + v1 * v1;
#pragma unroll
    for (int off = 32; off > 0; off >>= 1) {
      s += __shfl_down(s, off);
      s2 += __shfl_down(s2, off);
    }
    float* redS = (float*)(sm + 16640);
    float* redS2 = redS + 4;
    int wave = tid >> 6, lane = tid & 63;
    if (lane == 0) { redS[wave] = s; redS2[wave] = s2; }
    __syncthreads();
    float S = redS[0] + redS[1] + redS[2] + redS[3];
    float S2 = redS2[0] + redS2[1] + redS2[2] + redS2[3];
    float mean = S * (1.0f / 512.0f);
    float var = S2 * (1.0f / 512.0f) - mean * mean;
    float rstd = rsqrtf(var + 1e-5f);
    bf16* xnr = p.xn + (size_t)r * 512;
    xnr[tid] = (bf16)((v0 - mean) * rstd * p.ln_w[tid] + p.ln_b[tid]);
    xnr[tid + 256] = (bf16)((v1 - mean) * rstd * p.ln_w[tid + 256] + p.ln_b[tid + 256]);
    __syncthreads();  // redS reused if this block runs another unit
  }
}

// ---------- P2: proj GEMM (inline f32 W cvt) + a/c/d slice epilogue ----------
__device__ __forceinline__ void ph2(const P& p, int u, int tid) {
  int nb = u % 40, mb = u / 40;
  int n0 = nb * 64, m0 = mb * 64;
  int wave = tid >> 6, lane = tid & 63;
  int lq = lane >> 4, l16 = lane & 15;
  const bf16* Ap = p.xn + (size_t)(m0 + wave * 16 + l16) * 512;
  f32x4 acc[4];
#pragma unroll
  for (int nt = 0; nt < 4; nt++) acc[nt] = (f32x4){0.f, 0.f, 0.f, 0.f};
  for (int k0 = 0; k0 < 512; k0 += 32) {
    bf16x8 af = *(const bf16x8*)(Ap + k0 + lq * 8);
#pragma unroll
    for (int nt = 0; nt < 4; nt++) {
      f32x8 wv = *(const f32x8*)(p.Wab + (size_t)(n0 + nt * 16 + l16) * 512 + k0 + lq * 8);
      acc[nt] = MFMA_BF16(af, cvt8(wv), acc[nt]);
    }
  }
  int cm = m0 + wave * 16 + lq * 4;
#pragma unroll
  for (int nt = 0; nt < 4; nt++) {
    int n = n0 + nt * 16 + l16;
    int chunk = n >> 9, hcol = (n >> 6) & 7, i = n & 63;
#pragma unroll
    for (int rg = 0; rg < 4; rg++) {
      int m = cm + rg;
      float v = acc[nt][rg] + p.b_ab[n];
      p.proj[(size_t)m * 2560 + n] = v;
      bf16 bv = (bf16)v;
      if (chunk == 0) p.a[((size_t)hcol * SEQ + m) * 64 + i] = bv;
      else if (chunk == 2) p.c[(size_t)m * 512 + (n - 1024)] = bv;
      else if (chunk == 3) p.d[((size_t)hcol * SEQ + m) * 64 + i] = bv;
    }
  }
}

// ---------- P3: ecum(8) + bsum(3) + step1(192) + t(1536) ----------
__device__ __forceinline__ void ph3(const P& p, char* sm, int u, int tid) {
  if (u < 8) {  // per-head eT transpose + ecum prefix scan (64-row chunks, carried)
    int h = u;
    float* el = (float*)sm;
    float carry = 0.f;
    for (int ch = 0; ch < 3; ch++) {
      int pbase = ch * 64;
      if (ch) __syncthreads();
      for (int idx = tid; idx < 4096; idx += 256) {
        int pl = idx >> 6, g = idx & 63;
        el[pl * 65 + g] = p.proj[(size_t)(pbase + pl) * 2560 + 2048 + h * 64 + g];
      }
      __syncthreads();
      for (int idx = tid; idx < 4096; idx += 256) {
        int g = idx >> 6, ql = idx & 63;
        p.eT[((size_t)h * 64 + g) * SEQ + pbase + ql] = (bf16)el[ql * 65 + g];
      }
      if (tid < 64) {
        float run = carry;
        for (int pl = 0; pl < 64; pl++) {
          run += el[pl * 65 + tid];
          p.ecum[(size_t)h * 12288 + (pbase + pl) * 64 + tid] = run;
        }
        carry = run;
      }
      __syncthreads();
    }
  } else if (u < 11) {  // bsum
    int b3 = u - 8;
    int j = tid & 63, qg = tid >> 6;
#pragma unroll
    for (int qi = 0; qi < 16; qi++) {
      int q = b3 * 64 + qg * 16 + qi;
      float s = 0.f;
#pragma unroll
      for (int hh = 0; hh < 8; hh++) s += p.proj[(size_t)q * 2560 + 512 + hh * 64 + j];
      p.bsum[q * 64 + j] = (bf16)s;
    }
  } else if (u < 203) {  // step1: c @ WK2t^T (WK f32 read inline)
    int unit = u - 11;
    int nb = unit & 63, mb = unit >> 6;
    int n0 = nb * 64, m0 = mb * 64;
    int wave = tid >> 6, lane = tid & 63;
    int lq = lane >> 4, l16 = lane & 15;
    const bf16* Ap = p.c + (size_t)(m0 + wave * 16 + l16) * 512;
    f32x4 acc[4];
#pragma unroll
    for (int nt = 0; nt < 4; nt++) acc[nt] = (f32x4){0.f, 0.f, 0.f, 0.f};
    size_t offn[4];
#pragma unroll
    for (int nt = 0; nt < 4; nt++) {
      int n = n0 + nt * 16 + l16;
      offn[nt] = (size_t)(n >> 6) * 4096 + (size_t)(n & 63) * 64;
    }
    for (int k0 = 0; k0 < 512; k0 += 32) {
      bf16x8 af = *(const bf16x8*)(Ap + k0 + lq * 8);
      size_t kb = (size_t)(k0 >> 6) * 262144 + (k0 & 32) + lq * 8;
#pragma unroll
      for (int nt = 0; nt < 4; nt++) {
        f32x8 wv = *(const f32x8*)(p.WK + kb + offn[nt]);
        acc[nt] = MFMA_BF16(af, cvt8(wv), acc[nt]);
      }
    }
    int cm = m0 + wave * 16 + lq * 4;
#pragma unroll
    for (int nt = 0; nt < 4; nt++) {
      int n = n0 + nt * 16 + l16;
#pragma unroll
      for (int rg = 0; rg < 4; rg++) p.s1[(size_t)(cm + rg) * 4096 + n] = (bf16)acc[nt][rg];
    }
  } else {  // t[h] = d_h @ WVt2[h]^T -> row-major (consumer layout)
    int unit = u - 203;
    int h = unit / 192, rem = unit % 192;
    gemm_body<1>(p.d + (size_t)h * 12288, p.WVt2 + (size_t)h * 262144,
                 p.tTt + (size_t)h * 786432, 4096, 64, rem % 64, rem / 64, tid);
  }
}

// ---------- P5: scores+exp+ew(+ecum) per (r,h), ILP-batched ----------
__device__ __forceinline__ void ph5(const P& p, char* sm, int u, int tid) {
  int h = u & 7, r = u >> 3;
  int wave = tid >> 6, lane = tid & 63;
  int lq = lane >> 4, l16 = lane & 15;
  bf16* wch = (bf16*)sm;                 // [2][4][3][640]
  float* redL = (float*)(sm + 30720);
  int pt[3] = {wave, wave + 4, 11 - wave};

  const bf16* ah = p.a + (size_t)h * 12288;
  const bf16* s2r = p.s2 + (size_t)r * 12288;
  const bf16* eh = p.eT + (size_t)h * 12288;
  const float* ech = p.ecum + (size_t)h * 12288;

  bf16x8 afr[3][2];
#pragma unroll
  for (int mt = 0; mt < 3; mt++)
#pragma unroll
    for (int kc = 0; kc < 2; kc++)
      afr[mt][kc] = *(const bf16x8*)(ah + (pt[mt] * 16 + l16) * 64 + kc * 32 + lq * 8);

  f32x4 ewacc[3][4];
#pragma unroll
  for (int mt = 0; mt < 3; mt++)
#pragma unroll
    for (int nt = 0; nt < 4; nt++) ewacc[mt][nt] = (f32x4){0.f, 0.f, 0.f, 0.f};
  float lpart = 0.f;

  for (int cc = 0; cc < 6; cc++) {
    if (cc * 32 + 31 <= wave * 16) continue;
    int par = cc & 1;
    bf16x8 efr[4];
#pragma unroll
    for (int nt = 0; nt < 4; nt++)
      efr[nt] = *(const bf16x8*)(eh + (nt * 16 + l16) * SEQ + cc * 32 + lq * 8);
    bf16x8 bq[2][2];
#pragma unroll
    for (int sub = 0; sub < 2; sub++) {
      int q = cc * 32 + sub * 16 + l16;
      bq[sub][0] = *(const bf16x8*)(s2r + q * 64 + lq * 8);
      bq[sub][1] = *(const bf16x8*)(s2r + q * 64 + 32 + lq * 8);
    }
    f32x4 sacc[3][2];
#pragma unroll
    for (int mt = 0; mt < 3; mt++) {
      if (cc * 32 + 31 <= pt[mt] * 16) continue;
#pragma unroll
      for (int sub = 0; sub < 2; sub++) {
        if (cc * 32 + sub * 16 + 15 <= pt[mt] * 16) continue;
        f32x4 sv = (f32x4){0.f, 0.f, 0.f, 0.f};
        sv = MFMA_BF16(afr[mt][0], bq[sub][0], sv);
        sacc[mt][sub] = MFMA_BF16(afr[mt][1], bq[sub][1], sv);
      }
    }
#pragma unroll
    for (int mt = 0; mt < 3; mt++) {
      if (cc * 32 + 31 <= pt[mt] * 16) continue;
      bf16* mybuf = wch + ((par * 4 + wave) * 3 + mt) * 640;
#pragma unroll
      for (int sub = 0; sub < 2; sub++) {
        if (cc * 32 + sub * 16 + 15 <= pt[mt] * 16) {
#pragma unroll
          for (int rg = 0; rg < 4; rg++) mybuf[(lq * 4 + rg) * 40 + sub * 16 + l16] = (bf16)0.f;
          continue;
        }
        int q = cc * 32 + sub * 16 + l16;
        int p0 = pt[mt] * 16 + lq * 4;
#pragma unroll
        for (int rg = 0; rg < 4; rg++) {
          float wv = (q > p0 + rg) ? __expf(sacc[mt][sub][rg] * 0.015625f) : 0.f;
          lpart += wv;
          mybuf[(lq * 4 + rg) * 40 + sub * 16 + l16] = (bf16)wv;
        }
      }
    }
#pragma unroll
    for (int mt = 0; mt < 3; mt++) {
      if (cc * 32 + 31 <= pt[mt] * 16) continue;
      bf16x8 wf = *(const bf16x8*)(wch + ((par * 4 + wave) * 3 + mt) * 640 + l16 * 40 + lq * 8);
#pragma unroll
      for (int nt = 0; nt < 4; nt++) ewacc[mt][nt] = MFMA_BF16(wf, efr[nt], ewacc[mt][nt]);
    }
  }

  bf16* ewout = p.ew + ((size_t)h * SEQ + r) * 12288;
#pragma unroll
  for (int mt = 0; mt < 3; mt++)
#pragma unroll
    for (int nt = 0; nt < 4; nt++)
#pragma unroll
      for (int rg = 0; rg < 4; rg++) {
        int pp = pt[mt] * 16 + lq * 4 + rg;
        int g = nt * 16 + l16;
        ewout[pp * 64 + g] = (bf16)(ewacc[mt][nt][rg] + ech[pp * 64 + g]);
      }

#pragma unroll
  for (int off = 32; off > 0; off >>= 1) lpart += __shfl_down(lpart, off);
  if (lane == 0) redL[wave] = lpart;
  __syncthreads();
  if (tid == 0) p.Lsum[h * SEQ + r] = redL[0] + redL[1] + redL[2] + redL[3];
  __syncthreads();
}

// ---------- P6: Zpart[ks][r][h*64+f] = ew' @ tTt, 16-way K-split, 4 waves ----------
__device__ __forceinline__ void ph6(const P& p, char* sm, int u, int tid) {
  int ks = u & 15, mtb = (u >> 4) % 6, h = u / 96;
  int wave = tid >> 6, lane = tid & 63;
  int lq = lane >> 4, l16 = lane & 15;
  float* zred = (float*)sm;  // [4][16][66]
  const bf16* ewh = p.ew + ((size_t)h * SEQ + mtb * 32) * 12288;
  const bf16* th = p.tTt + (size_t)h * 786432;
  f32x4 acc[2][4];
#pragma unroll
  for (int m2 = 0; m2 < 2; m2++)
#pragma unroll
    for (int nt = 0; nt < 4; nt++) acc[m2][nt] = (f32x4){0.f, 0.f, 0.f, 0.f};
#pragma unroll
  for (int jj = 0; jj < 6; jj++) {
    int kc = ks * 24 + wave * 6 + jj;
    int pp = kc >> 1, g0 = (kc & 1) * 32;
    bf16x8 af0 = *(const bf16x8*)(ewh + (size_t)l16 * 12288 + kc * 32 + lq * 8);
    bf16x8 af1 = *(const bf16x8*)(ewh + (size_t)(16 + l16) * 12288 + kc * 32 + lq * 8);
#pragma unroll
    for (int nt = 0; nt < 4; nt++) {
      bf16x8 tf = *(const bf16x8*)(th + (size_t)pp * 4096 + (nt * 16 + l16) * 64 + g0 + lq * 8);
      acc[0][nt] = MFMA_BF16(af0, tf, acc[0][nt]);
      acc[1][nt] = MFMA_BF16(af1, tf, acc[1][nt]);
    }
  }
#pragma unroll
  for (int m2 = 0; m2 < 2; m2++) {
    if (m2) __syncthreads();
#pragma unroll
    for (int nt = 0; nt < 4; nt++)
#pragma unroll
      for (int rg = 0; rg < 4; rg++)
        zred[(wave * 16 + lq * 4 + rg) * 66 + nt * 16 + l16] = acc[m2][nt][rg];
    __syncthreads();
#pragma unroll
    for (int o = 0; o < 4; o++) {
      int idx = o * 256 + tid;  // 1024 outputs [rloc16][f64]
      int rloc = idx >> 6, f = idx & 63;
      float s = zred[rloc * 66 + f] + zred[(16 + rloc) * 66 + f] + zred[(32 + rloc) * 66 + f] +
                zred[(48 + rloc) * 66 + f];
      p.Zpart[(size_t)ks * 98304 + (size_t)(mtb * 32 + m2 * 16 + rloc) * 512 + h * 64 + f] = s;
    }
  }
  __syncthreads();  // zred reused if this block runs another unit
}

// ---------- P7: z built in LDS from 16 Zpart slices (/L), then out = z @ Wout^T + b ----------
__device__ __forceinline__ void ph7(const P& p, char* sm, int u, int tid) {
  int mb = u >> 3, nb = u & 7;
  bf16* zt = (bf16*)sm;                 // 16 x 520 (padded)
  float* rd = (float*)(sm + 16640);     // [4][16][68]
  for (int idx = tid; idx < 8192; idx += 256) {
    int m = idx >> 9, cc = idx & 511;
    float s = 0.f;
#pragma unroll
    for (int ks = 0; ks < 16; ks++)
      s += p.Zpart[(size_t)ks * 98304 + (size_t)(mb * 16 + m) * 512 + cc];
    float L = p.Lsum[(cc >> 6) * SEQ + mb * 16 + m] + 18528.0f;  // masked mass, w == 1.0f
    zt[m * 520 + cc] = (bf16)(s / L);
  }
  __syncthreads();
  int wave = tid >> 6, lane = tid & 63;
  int lq = lane >> 4, l16 = lane & 15;
  f32x4 acc[4];
#pragma unroll
  for (int nt = 0; nt < 4; nt++) acc[nt] = (f32x4){0.f, 0.f, 0.f, 0.f};
#pragma unroll
  for (int kc = 0; kc < 4; kc++) {
    int k0 = wave * 128 + kc * 32;
    bf16x8 af = *(const bf16x8*)(zt + l16 * 520 + k0 + lq * 8);
#pragma unroll
    for (int nt = 0; nt < 4; nt++) {
      f32x8 wv = *(const f32x8*)(p.Wout + (size_t)(nb * 64 + nt * 16 + l16) * 512 + k0 + lq * 8);
      acc[nt] = MFMA_BF16(af, cvt8(wv), acc[nt]);
    }
  }
  __syncthreads();
#pragma unroll
  for (int nt = 0; nt < 4; nt++)
#pragma unroll
    for (int rg = 0; rg < 4; rg++)
      rd[(wave * 16 + lq * 4 + rg) * 68 + nt * 16 + l16] = acc[nt][rg];
  __syncthreads();
#pragma unroll
  for (int o = 0; o < 4; o++) {
    int idx = o * 256 + tid;
    int rloc = idx >> 6, f = idx & 63;
    float s = rd[rloc * 68 + f] + rd[(16 + rloc) * 68 + f] + rd[(32 + rloc) * 68 + f] +
              rd[(48 + rloc) * 68 + f];
    p.out[(size_t)(mb * 16 + rloc) * 512 + nb * 64 + f] = s + p.b_out[nb * 64 + f];
  }
}

// =================== single cooperative kernel (2 blocks/CU guaranteed) ===================
__global__ __launch_bounds__(256, 2) void mega(P p) {
  cg::grid_group grid = cg::this_grid();
  __shared__ __align__(16) char sm[34816];
  int tid = threadIdx.x;
  for (int u = blockIdx.x; u < 704; u += GRID) ph1(p, sm, u, tid);
  grid.sync();
  for (int u = blockIdx.x; u < 120; u += GRID) ph2(p, u, tid);
  grid.sync();
  for (int u = blockIdx.x; u < 1739; u += GRID) ph3(p, sm, u, tid);
  grid.sync();
  for (int u = blockIdx.x; u < 576; u += GRID)
    gemm_body<2>(p.s1, p.bsum, p.s2, 192, 64, u % 3, u / 3, tid);
  grid.sync();
  for (int u = blockIdx.x; u < 1536; u += GRID) ph5(p, sm, u, tid);
  grid.sync();
  for (int u = blockIdx.x; u < 768; u += GRID) ph6(p, sm, u, tid);
  grid.sync();
  for (int u = blockIdx.x; u < 96; u += GRID) ph7(p, sm, u, tid);
}

// =================== fallback wrappers (plain dispatches, same phase bodies) ===================
__global__ __launch_bounds__(256) void g1(P p) {
  __shared__ __align__(16) char sm[16672];
  ph1(p, sm, blockIdx.x, threadIdx.x);
}
__global__ __launch_bounds__(256) void g2(P p) { ph2(p, blockIdx.x, threadIdx.x); }
__global__ __launch_bounds__(256) void g3(P p) {
  __shared__ __align__(16) char sm[16640];
  ph3(p, sm, blockIdx.x, threadIdx.x);
}
__global__ __launch_bounds__(256) void g4(P p) {
  int u = blockIdx.x;
  gemm_body<2>(p.s1, p.bsum, p.s2, 192, 64, u % 3, u / 3, threadIdx.x);
}
__global__ __launch_bounds__(256, 3) void g5(P p) {
  __shared__ __align__(16) char sm[30736];
  ph5(p, sm, blockIdx.x, threadIdx.x);
}
__global__ __launch_bounds__(256) void g6(P p) {
  __shared__ __align__(16) char sm[16896];
  ph6(p, sm, blockIdx.x, threadIdx.x);
}
__global__ __launch_bounds__(256) void g7(P p) {
  __shared__ __align__(16) char sm[34048];
  ph7(p, sm, blockIdx.x, threadIdx.x);
}

// =================== workspace layout (f32 units) ===================
static const size_t OFF_PROJ = 0;         // f32 491520
static const size_t OFF_ECUM = 491520;    // f32 98304
static const size_t OFF_XN = 589824;      // bf16 -> 49152
static const size_t OFF_LSUM = 638976;    // f32 1536
static const size_t OFF_ZPART = 640512;   // f32 1572864 (16 slices x 98304)
static const size_t OFF_WVT = 2213376;    // bf16 -> 1048576
static const size_t OFF_A = 3261952;      // bf16 -> 49152
static const size_t OFF_C = 3311104;      // 49152
static const size_t OFF_D = 3360256;      // 49152
static const size_t OFF_ET = 3409408;     // 49152
static const size_t OFF_BSUM = 3458560;   // 6144
static const size_t OFF_S1 = 3464704;     // bf16 -> 393216
static const size_t OFF_S2 = 3857920;     // bf16 -> 1179648
static const size_t OFF_TT = 5037568;     // bf16 -> 3145728
static const size_t OFF_EW = 8183296;     // bf16 -> 9437184
// TOTAL = 17620480 f32 = 70.5 MB

extern "C" void kernel_launch(void* const* d_in, const int* in_sizes, int n_in,
                              void* d_out, int out_size, void* d_ws, size_t ws_size,
                              hipStream_t stream) {
  (void)in_sizes; (void)n_in; (void)out_size; (void)ws_size;
  float* ws = (float*)d_ws;
  P p;
  p.x = (const float*)d_in[0];
  p.ln_w = (const float*)d_in[1];
  p.ln_b = (const float*)d_in[2];
  p.Wab = (const float*)d_in[3];
  p.b_ab = (const float*)d_in[4];
  p.WK = (const float*)d_in[5];
  p.WV = (const float*)d_in[6];
  p.Wout = (const float*)d_in[7];
  p.b_out = (const float*)d_in[8];
  p.out = (float*)d_out;
  p.proj = ws + OFF_PROJ;
  p.ecum = ws + OFF_ECUM;
  p.Zpart = ws + OFF_ZPART;
  p.Lsum = ws + OFF_LSUM;
  p.xn = (bf16*)(ws + OFF_XN);
  p.WVt2 = (bf16*)(ws + OFF_WVT);
  p.a = (bf16*)(ws + OFF_A);
  p.c = (bf16*)(ws + OFF_C);
  p.d = (bf16*)(ws + OFF_D);
  p.eT = (bf16*)(ws + OFF_ET);
  p.bsum = (bf16*)(ws + OFF_BSUM);
  p.s1 = (bf16*)(ws + OFF_S1);
  p.s2 = (bf16*)(ws + OFF_S2);
  p.tTt = (bf16*)(ws + OFF_TT);
  p.ew = (bf16*)(ws + OFF_EW);

  void* args[] = {(void*)&p};
  hipError_t err = hipLaunchCooperativeKernel((const void*)mega, dim3(GRID), dim3(256), args,
                                              0, stream);
  if (err != hipSuccess) {
    (void)hipGetLastError();  // clear sticky error; fall back to plain dispatches
    g1<<<704, 256, 0, stream>>>(p);
    g2<<<120, 256, 0, stream>>>(p);
    g3<<<1739, 256, 0, stream>>>(p);
    g4<<<576, 256, 0, stream>>>(p);
    g5<<<1536, 256, 0, stream>>>(p);
    g6<<<768, 256, 0, stream>>>(p);
    g7<<<96, 256, 0, stream>>>(p);
  }
}

// Round 11
// 221.029 us; speedup vs baseline: 2.6615x; 2.6615x over previous
//
#include <hip/hip_runtime.h>
#include <hip/hip_bf16.h>
#include <cstdint>

#define SEQ 192

typedef float f32x4 __attribute__((ext_vector_type(4)));
typedef float f32x8 __attribute__((ext_vector_type(8)));
typedef __bf16 bf16;
typedef __bf16 bf16x8 __attribute__((ext_vector_type(8)));
typedef __bf16 bf16x4 __attribute__((ext_vector_type(4)));

#define MFMA_BF16(a, b, c) __builtin_amdgcn_mfma_f32_16x16x32_bf16(a, b, c, 0, 0, 0)

__device__ __forceinline__ bf16x8 cvt8(f32x8 v) {
  bf16x8 o;
#pragma unroll
  for (int i = 0; i < 8; i++) o[i] = (bf16)v[i];
  return o;
}

// =================== K1: WVt2 transpose + LayerNorm (R8, proven) ===================
__global__ __launch_bounds__(256) void k1_prep(
    const float* __restrict__ x, const float* __restrict__ ln_w, const float* __restrict__ ln_b,
    const float* __restrict__ WV, bf16* __restrict__ xn_bf, bf16* __restrict__ WVt2) {
  int bid = blockIdx.x, tid = threadIdx.x;
  if (bid < 512) {
    int g = bid & 63, hh = bid >> 6;
    __shared__ float ld[64 * 65];
    int f = tid & 63, r4 = tid >> 6;
#pragma unroll
    for (int it = 0; it < 16; it++) {
      int hp = it * 4 + r4;
      ld[hp * 65 + f] = WV[(((size_t)(hh * 64 + hp) * 64 + g) * 64) + f];
    }
    __syncthreads();
    int hp2 = tid & 63;
#pragma unroll
    for (int it = 0; it < 16; it++) {
      int ff = it * 4 + r4;
      WVt2[(size_t)hh * 262144 + (size_t)(ff * 64 + g) * 64 + hp2] = (bf16)ld[hp2 * 65 + ff];
    }
    return;
  }
  bid -= 512;
  {
    int r = bid;
    const float* xr = x + (size_t)r * 512;
    float v0 = xr[tid], v1 = xr[tid + 256];
    float s = v0 + v1, s2 = v0 * v0 + v1 * v1;
#pragma unroll
    for (int off = 32; off > 0; off >>= 1) {
      s += __shfl_down(s, off);
      s2 += __shfl_down(s2, off);
    }
    __shared__ float redS[4], redS2[4];
    int wave = tid >> 6, lane = tid & 63;
    if (lane == 0) { redS[wave] = s; redS2[wave] = s2; }
    __syncthreads();
    float S = redS[0] + redS[1] + redS[2] + redS[3];
    float S2 = redS2[0] + redS2[1] + redS2[2] + redS2[3];
    float mean = S * (1.0f / 512.0f);
    float var = S2 * (1.0f / 512.0f) - mean * mean;
    float rstd = rsqrtf(var + 1e-5f);
    bf16* xnr = xn_bf + (size_t)r * 512;
    xnr[tid] = (bf16)((v0 - mean) * rstd * ln_w[tid] + ln_b[tid]);
    xnr[tid + 256] = (bf16)((v1 - mean) * rstd * ln_w[tid + 256] + ln_b[tid + 256]);
  }
}

// ---------- LDS-free bf16 GEMM core (MODE1: bf16 row-major out) ----------
__device__ __forceinline__ void gemm_rm(const bf16* __restrict__ A, const bf16* __restrict__ Bt,
                                        bf16* __restrict__ C1, int N, int K, int nb, int mb,
                                        int tid) {
  int n0 = nb * 64, m0 = mb * 64;
  int wave = tid >> 6, lane = tid & 63;
  int lq = lane >> 4, l16 = lane & 15;
  const bf16* Ap = A + (size_t)(m0 + wave * 16 + l16) * K;
  f32x4 acc[4];
#pragma unroll
  for (int nt = 0; nt < 4; nt++) acc[nt] = (f32x4){0.f, 0.f, 0.f, 0.f};
  for (int k0 = 0; k0 < K; k0 += 32) {
    bf16x8 af = *(const bf16x8*)(Ap + k0 + lq * 8);
#pragma unroll
    for (int nt = 0; nt < 4; nt++) {
      bf16x8 bv = *(const bf16x8*)(Bt + (size_t)(n0 + nt * 16 + l16) * K + k0 + lq * 8);
      acc[nt] = MFMA_BF16(af, bv, acc[nt]);
    }
  }
  int cm = m0 + wave * 16 + lq * 4;
#pragma unroll
  for (int nt = 0; nt < 4; nt++) {
    int n = n0 + nt * 16 + l16;
#pragma unroll
    for (int rg = 0; rg < 4; rg++) C1[(size_t)(cm + rg) * N + n] = (bf16)acc[nt][rg];
  }
}

// =================== K2: proj GEMM + slice epilogue (R8, proven) ===================
__global__ __launch_bounds__(256) void k2_proj(
    const bf16* __restrict__ xn_bf, const float* __restrict__ Wab,
    const float* __restrict__ b_abcde, float* __restrict__ proj, bf16* __restrict__ a_bf,
    bf16* __restrict__ c_bf, bf16* __restrict__ d_bf) {
  int bid = blockIdx.x, tid = threadIdx.x;
  int nb = bid % 40, mb = bid / 40;
  int n0 = nb * 64, m0 = mb * 64;
  int wave = tid >> 6, lane = tid & 63;
  int lq = lane >> 4, l16 = lane & 15;
  const bf16* Ap = xn_bf + (size_t)(m0 + wave * 16 + l16) * 512;
  f32x4 acc[4];
#pragma unroll
  for (int nt = 0; nt < 4; nt++) acc[nt] = (f32x4){0.f, 0.f, 0.f, 0.f};
  for (int k0 = 0; k0 < 512; k0 += 32) {
    bf16x8 af = *(const bf16x8*)(Ap + k0 + lq * 8);
#pragma unroll
    for (int nt = 0; nt < 4; nt++) {
      f32x8 wv = *(const f32x8*)(Wab + (size_t)(n0 + nt * 16 + l16) * 512 + k0 + lq * 8);
      acc[nt] = MFMA_BF16(af, cvt8(wv), acc[nt]);
    }
  }
  int cm = m0 + wave * 16 + lq * 4;
#pragma unroll
  for (int nt = 0; nt < 4; nt++) {
    int n = n0 + nt * 16 + l16;
    int chunk = n >> 9, hcol = (n >> 6) & 7, i = n & 63;
#pragma unroll
    for (int rg = 0; rg < 4; rg++) {
      int m = cm + rg;
      float v = acc[nt][rg] + b_abcde[n];
      proj[(size_t)m * 2560 + n] = v;
      bf16 bv = (bf16)v;
      if (chunk == 0) a_bf[((size_t)hcol * SEQ + m) * 64 + i] = bv;
      else if (chunk == 2) c_bf[(size_t)m * 512 + (n - 1024)] = bv;
      else if (chunk == 3) d_bf[((size_t)hcol * SEQ + m) * 64 + i] = bv;
    }
  }
}

// =================== K3: step1 + t GEMM + eT/ecum + bsum (R8, proven) ===================
__global__ __launch_bounds__(256) void k3_mid(
    const bf16* __restrict__ c_bf, const float* __restrict__ WK, bf16* __restrict__ s1bf,
    const bf16* __restrict__ d_bf, const bf16* __restrict__ WVt2, bf16* __restrict__ tTt,
    const float* __restrict__ proj, bf16* __restrict__ eT_bf, float* __restrict__ ecum,
    bf16* __restrict__ bsum_bf) {
  __shared__ float el[64 * 65];
  int bid = blockIdx.x, tid = threadIdx.x;
  if (bid < 192) {
    int nb = bid % 64, mb = bid / 64;
    int n0 = nb * 64, m0 = mb * 64;
    int wave = tid >> 6, lane = tid & 63;
    int lq = lane >> 4, l16 = lane & 15;
    const bf16* Ap = c_bf + (size_t)(m0 + wave * 16 + l16) * 512;
    f32x4 acc[4];
#pragma unroll
    for (int nt = 0; nt < 4; nt++) acc[nt] = (f32x4){0.f, 0.f, 0.f, 0.f};
    size_t offn[4];
#pragma unroll
    for (int nt = 0; nt < 4; nt++) {
      int n = n0 + nt * 16 + l16;
      offn[nt] = (size_t)(n >> 6) * 4096 + (size_t)(n & 63) * 64;
    }
    for (int k0 = 0; k0 < 512; k0 += 32) {
      bf16x8 af = *(const bf16x8*)(Ap + k0 + lq * 8);
      size_t kb = (size_t)(k0 >> 6) * 262144 + (k0 & 32) + lq * 8;
#pragma unroll
      for (int nt = 0; nt < 4; nt++) {
        f32x8 wv = *(const f32x8*)(WK + kb + offn[nt]);
        acc[nt] = MFMA_BF16(af, cvt8(wv), acc[nt]);
      }
    }
    int cm = m0 + wave * 16 + lq * 4;
#pragma unroll
    for (int nt = 0; nt < 4; nt++) {
      int n = n0 + nt * 16 + l16;
#pragma unroll
      for (int rg = 0; rg < 4; rg++) s1bf[(size_t)(cm + rg) * 4096 + n] = (bf16)acc[nt][rg];
    }
    return;
  }
  bid -= 192;
  if (bid < 1536) {
    int h = bid / 192, rem = bid % 192;
    gemm_rm(d_bf + (size_t)h * 12288, WVt2 + (size_t)h * 262144,
            tTt + (size_t)h * 786432, 4096, 64, rem % 64, rem / 64, tid);
    return;
  }
  bid -= 1536;
  if (bid < 8) {
    int h = bid;
    float carry = 0.f;
    for (int ch = 0; ch < 3; ch++) {
      int pbase = ch * 64;
      if (ch) __syncthreads();
      for (int idx = tid; idx < 4096; idx += 256) {
        int pl = idx >> 6, g = idx & 63;
        el[pl * 65 + g] = proj[(size_t)(pbase + pl) * 2560 + 2048 + h * 64 + g];
      }
      __syncthreads();
      for (int idx = tid; idx < 4096; idx += 256) {
        int g = idx >> 6, ql = idx & 63;
        eT_bf[((size_t)h * 64 + g) * SEQ + pbase + ql] = (bf16)el[ql * 65 + g];
      }
      if (tid < 64) {
        float run = carry;
        for (int pl = 0; pl < 64; pl++) {
          run += el[pl * 65 + tid];
          ecum[(size_t)h * 12288 + (pbase + pl) * 64 + tid] = run;
        }
        carry = run;
      }
      __syncthreads();
    }
    return;
  }
  bid -= 8;
  {
    int j = tid & 63, qg = tid >> 6;
#pragma unroll
    for (int qi = 0; qi < 16; qi++) {
      int q = bid * 64 + qg * 16 + qi;
      float s = 0.f;
#pragma unroll
      for (int hh = 0; hh < 8; hh++) s += proj[(size_t)q * 2560 + 512 + hh * 64 + j];
      bsum_bf[q * 64 + j] = (bf16)s;
    }
  }
}

// =================== K45: inline-step2 + scores + exp + ew(+ecum) per (r,h) ===================
// Phase A: s2L[q][i] = sum_j s1[r][i*64+j]*bsum[q][j] via MFMA into padded LDS (stride 72).
// Phase B: R7-proven ILP-batched scores->exp->ew, bq read from s2L.
__global__ __launch_bounds__(256, 3) void k45_attn(
    const bf16* __restrict__ a_bf, const bf16* __restrict__ s1bf,
    const bf16* __restrict__ bsum_bf, const bf16* __restrict__ eT_bf,
    const float* __restrict__ ecum, bf16* __restrict__ ew_bf, float* __restrict__ Lsum) {
  int r = blockIdx.x, h = blockIdx.y;
  int tid = threadIdx.x, wave = tid >> 6, lane = tid & 63;
  int lq = lane >> 4, l16 = lane & 15;
  __shared__ __align__(16) bf16 s2L[SEQ * 72];       // 27.6 KB, [q][i] stride 72
  __shared__ __align__(16) bf16 wch[4][3][16 * 40];  // 15.4 KB
  __shared__ float redL[4];

  // ---- Phase A: s2[r] inline (wave = i-tile) ----
  {
    const bf16* s1r = s1bf + (size_t)r * 4096;
    bf16x8 aS[2];
#pragma unroll
    for (int kc = 0; kc < 2; kc++)
      aS[kc] = *(const bf16x8*)(s1r + (wave * 16 + l16) * 64 + kc * 32 + lq * 8);
#pragma unroll
    for (int qt = 0; qt < 12; qt++) {
      f32x4 acc = (f32x4){0.f, 0.f, 0.f, 0.f};
#pragma unroll
      for (int kc = 0; kc < 2; kc++) {
        bf16x8 bv = *(const bf16x8*)(bsum_bf + (qt * 16 + l16) * 64 + kc * 32 + lq * 8);
        acc = MFMA_BF16(aS[kc], bv, acc);
      }
      bf16x4 pk = {(bf16)acc[0], (bf16)acc[1], (bf16)acc[2], (bf16)acc[3]};
      *(bf16x4*)(&s2L[(qt * 16 + l16) * 72 + wave * 16 + lq * 4]) = pk;
    }
  }
  __syncthreads();

  // ---- Phase B ----
  int pt[3] = {wave, wave + 4, 11 - wave};
  const bf16* ah = a_bf + (size_t)h * 12288;
  const bf16* eh = eT_bf + (size_t)h * 12288;
  const float* ech = ecum + (size_t)h * 12288;

  bf16x8 afr[3][2];
#pragma unroll
  for (int mt = 0; mt < 3; mt++)
#pragma unroll
    for (int kc = 0; kc < 2; kc++)
      afr[mt][kc] = *(const bf16x8*)(ah + (pt[mt] * 16 + l16) * 64 + kc * 32 + lq * 8);

  f32x4 ewacc[3][4];
#pragma unroll
  for (int mt = 0; mt < 3; mt++)
#pragma unroll
    for (int nt = 0; nt < 4; nt++) ewacc[mt][nt] = (f32x4){0.f, 0.f, 0.f, 0.f};
  float lpart = 0.f;

  for (int cc = 0; cc < 6; cc++) {
    if (cc * 32 + 31 <= wave * 16) continue;
    bf16x8 efr[4];
#pragma unroll
    for (int nt = 0; nt < 4; nt++)
      efr[nt] = *(const bf16x8*)(eh + (nt * 16 + l16) * SEQ + cc * 32 + lq * 8);
    bf16x8 bq[2][2];
#pragma unroll
    for (int sub = 0; sub < 2; sub++) {
      int q = cc * 32 + sub * 16 + l16;
      bq[sub][0] = *(const bf16x8*)(&s2L[q * 72 + lq * 8]);
      bq[sub][1] = *(const bf16x8*)(&s2L[q * 72 + 32 + lq * 8]);
    }
    f32x4 sacc[3][2];
#pragma unroll
    for (int mt = 0; mt < 3; mt++) {
      if (cc * 32 + 31 <= pt[mt] * 16) continue;
#pragma unroll
      for (int sub = 0; sub < 2; sub++) {
        if (cc * 32 + sub * 16 + 15 <= pt[mt] * 16) continue;
        f32x4 sv = (f32x4){0.f, 0.f, 0.f, 0.f};
        sv = MFMA_BF16(afr[mt][0], bq[sub][0], sv);
        sacc[mt][sub] = MFMA_BF16(afr[mt][1], bq[sub][1], sv);
      }
    }
#pragma unroll
    for (int mt = 0; mt < 3; mt++) {
      if (cc * 32 + 31 <= pt[mt] * 16) continue;
      bf16* mybuf = &wch[wave][mt][0];
#pragma unroll
      for (int sub = 0; sub < 2; sub++) {
        if (cc * 32 + sub * 16 + 15 <= pt[mt] * 16) {
#pragma unroll
          for (int rg = 0; rg < 4; rg++) mybuf[(lq * 4 + rg) * 40 + sub * 16 + l16] = (bf16)0.f;
          continue;
        }
        int q = cc * 32 + sub * 16 + l16;
        int p0 = pt[mt] * 16 + lq * 4;
#pragma unroll
        for (int rg = 0; rg < 4; rg++) {
          float wv = (q > p0 + rg) ? __expf(sacc[mt][sub][rg] * 0.015625f) : 0.f;
          lpart += wv;
          mybuf[(lq * 4 + rg) * 40 + sub * 16 + l16] = (bf16)wv;
        }
      }
    }
#pragma unroll
    for (int mt = 0; mt < 3; mt++) {
      if (cc * 32 + 31 <= pt[mt] * 16) continue;
      bf16x8 wf = *(const bf16x8*)(&wch[wave][mt][l16 * 40 + lq * 8]);
#pragma unroll
      for (int nt = 0; nt < 4; nt++) ewacc[mt][nt] = MFMA_BF16(wf, efr[nt], ewacc[mt][nt]);
    }
  }

  bf16* ewout = ew_bf + ((size_t)h * SEQ + r) * 12288;
#pragma unroll
  for (int mt = 0; mt < 3; mt++)
#pragma unroll
    for (int nt = 0; nt < 4; nt++)
#pragma unroll
      for (int rg = 0; rg < 4; rg++) {
        int pp = pt[mt] * 16 + lq * 4 + rg;
        int g = nt * 16 + l16;
        ewout[pp * 64 + g] = (bf16)(ewacc[mt][nt][rg] + ech[pp * 64 + g]);
      }

#pragma unroll
  for (int off = 32; off > 0; off >>= 1) lpart += __shfl_down(lpart, off);
  if (lane == 0) redL[wave] = lpart;
  __syncthreads();
  if (tid == 0) Lsum[h * SEQ + r] = redL[0] + redL[1] + redL[2] + redL[3];
}

// =================== K5b: Zpart[ks<8] = ew' @ tTt (R8, proven) ===================
__global__ __launch_bounds__(512) void k5b_z(
    const bf16* __restrict__ ew_bf, const bf16* __restrict__ tTt, float* __restrict__ Zpart) {
  int h = blockIdx.x, mt = blockIdx.y, ks = blockIdx.z;
  int tid = threadIdx.x, wave = tid >> 6, lane = tid & 63;
  int lq = lane >> 4, l16 = lane & 15;
  __shared__ float zred[8][16][66];
  const bf16* ewh = ew_bf + ((size_t)h * SEQ + mt * 32) * 12288;
  const bf16* th = tTt + (size_t)h * 786432;
  f32x4 acc[2][4];
#pragma unroll
  for (int m2 = 0; m2 < 2; m2++)
#pragma unroll
    for (int nt = 0; nt < 4; nt++) acc[m2][nt] = (f32x4){0.f, 0.f, 0.f, 0.f};
  for (int jj = 0; jj < 6; jj++) {
    int kc = ks * 48 + wave * 6 + jj;
    int pp = kc >> 1, g0 = (kc & 1) * 32;
    bf16x8 af0 = *(const bf16x8*)(ewh + (size_t)l16 * 12288 + kc * 32 + lq * 8);
    bf16x8 af1 = *(const bf16x8*)(ewh + (size_t)(16 + l16) * 12288 + kc * 32 + lq * 8);
#pragma unroll
    for (int nt = 0; nt < 4; nt++) {
      bf16x8 tf = *(const bf16x8*)(th + (size_t)pp * 4096 + (nt * 16 + l16) * 64 + g0 + lq * 8);
      acc[0][nt] = MFMA_BF16(af0, tf, acc[0][nt]);
      acc[1][nt] = MFMA_BF16(af1, tf, acc[1][nt]);
    }
  }
#pragma unroll
  for (int m2 = 0; m2 < 2; m2++) {
    if (m2) __syncthreads();
#pragma unroll
    for (int nt = 0; nt < 4; nt++)
#pragma unroll
      for (int rg = 0; rg < 4; rg++) zred[wave][lq * 4 + rg][nt * 16 + l16] = acc[m2][nt][rg];
    __syncthreads();
#pragma unroll
    for (int o = 0; o < 2; o++) {
      int idx = o * 512 + tid;
      int rloc = idx >> 6, f = idx & 63;
      float s = 0.f;
#pragma unroll
      for (int wv = 0; wv < 8; wv++) s += zred[wv][rloc][f];
      Zpart[(size_t)ks * 98304 + (size_t)(mt * 32 + m2 * 16 + rloc) * 512 + h * 64 + f] = s;
    }
  }
}

// =================== K6: z in LDS from 8 Zpart slices (/L) + out GEMM (ph7, proven) ===================
__global__ __launch_bounds__(256) void k6_out(
    const float* __restrict__ Zpart, const float* __restrict__ Lsum,
    const float* __restrict__ Wout, const float* __restrict__ b_out, float* __restrict__ out) {
  int u = blockIdx.x, tid = threadIdx.x;
  int mb = u >> 3, nb = u & 7;
  __shared__ __align__(16) bf16 zt[16 * 520];
  __shared__ float rd[4 * 16 * 68];
  for (int idx = tid; idx < 8192; idx += 256) {
    int m = idx >> 9, cc = idx & 511;
    float s = 0.f;
#pragma unroll
    for (int ks = 0; ks < 8; ks++)
      s += Zpart[(size_t)ks * 98304 + (size_t)(mb * 16 + m) * 512 + cc];
    float L = Lsum[(cc >> 6) * SEQ + mb * 16 + m] + 18528.0f;  // masked mass, w == 1.0f
    zt[m * 520 + cc] = (bf16)(s / L);
  }
  __syncthreads();
  int wave = tid >> 6, lane = tid & 63;
  int lq = lane >> 4, l16 = lane & 15;
  f32x4 acc[4];
#pragma unroll
  for (int nt = 0; nt < 4; nt++) acc[nt] = (f32x4){0.f, 0.f, 0.f, 0.f};
#pragma unroll
  for (int kc = 0; kc < 4; kc++) {
    int k0 = wave * 128 + kc * 32;
    bf16x8 af = *(const bf16x8*)(zt + l16 * 520 + k0 + lq * 8);
#pragma unroll
    for (int nt = 0; nt < 4; nt++) {
      f32x8 wv = *(const f32x8*)(Wout + (size_t)(nb * 64 + nt * 16 + l16) * 512 + k0 + lq * 8);
      acc[nt] = MFMA_BF16(af, cvt8(wv), acc[nt]);
    }
  }
#pragma unroll
  for (int nt = 0; nt < 4; nt++)
#pragma unroll
    for (int rg = 0; rg < 4; rg++)
      rd[(wave * 16 + lq * 4 + rg) * 68 + nt * 16 + l16] = acc[nt][rg];
  __syncthreads();
#pragma unroll
  for (int o = 0; o < 4; o++) {
    int idx = o * 256 + tid;
    int rloc = idx >> 6, f = idx & 63;
    float s = rd[rloc * 68 + f] + rd[(16 + rloc) * 68 + f] + rd[(32 + rloc) * 68 + f] +
              rd[(48 + rloc) * 68 + f];
    out[(size_t)(mb * 16 + rloc) * 512 + nb * 64 + f] = s + b_out[nb * 64 + f];
  }
}

// =================== workspace layout (f32 units) ===================
static const size_t OFF_PROJ = 0;         // f32 491520
static const size_t OFF_ECUM = 491520;    // f32 98304
static const size_t OFF_XN = 589824;      // bf16 -> 49152
static const size_t OFF_LSUM = 638976;    // f32 1536
static const size_t OFF_ZPART = 640512;   // f32 786432 (8 slices)
static const size_t OFF_WVT = 2213376;    // bf16 -> 1048576
static const size_t OFF_A = 3261952;      // bf16 -> 49152
static const size_t OFF_C = 3311104;      // 49152
static const size_t OFF_D = 3360256;      // 49152
static const size_t OFF_ET = 3409408;     // 49152
static const size_t OFF_BSUM = 3458560;   // 6144
static const size_t OFF_S1 = 3464704;     // bf16 -> 393216
static const size_t OFF_TT = 5037568;     // bf16 -> 3145728
static const size_t OFF_EW = 8183296;     // bf16 -> 9437184
// TOTAL = 17620480 f32 = 70.5 MB

extern "C" void kernel_launch(void* const* d_in, const int* in_sizes, int n_in,
                              void* d_out, int out_size, void* d_ws, size_t ws_size,
                              hipStream_t stream) {
  (void)in_sizes; (void)n_in; (void)out_size; (void)ws_size;
  const float* x = (const float*)d_in[0];
  const float* ln_w = (const float*)d_in[1];
  const float* ln_b = (const float*)d_in[2];
  const float* W_abcde = (const float*)d_in[3];
  const float* b_abcde = (const float*)d_in[4];
  const float* W_K = (const float*)d_in[5];
  const float* W_V = (const float*)d_in[6];
  const float* W_out = (const float*)d_in[7];
  const float* b_out = (const float*)d_in[8];
  float* out = (float*)d_out;
  float* ws = (float*)d_ws;

  float* proj = ws + OFF_PROJ;
  float* ecum = ws + OFF_ECUM;
  bf16* xn_bf = (bf16*)(ws + OFF_XN);
  float* Lsum = ws + OFF_LSUM;
  float* Zpart = ws + OFF_ZPART;
  bf16* WVt2 = (bf16*)(ws + OFF_WVT);
  bf16* a_bf = (bf16*)(ws + OFF_A);
  bf16* c_bf = (bf16*)(ws + OFF_C);
  bf16* d_bf = (bf16*)(ws + OFF_D);
  bf16* eT_bf = (bf16*)(ws + OFF_ET);
  bf16* bsum_bf = (bf16*)(ws + OFF_BSUM);
  bf16* s1bf = (bf16*)(ws + OFF_S1);
  bf16* tTt = (bf16*)(ws + OFF_TT);
  bf16* ew_bf = (bf16*)(ws + OFF_EW);

  k1_prep<<<704, 256, 0, stream>>>(x, ln_w, ln_b, W_V, xn_bf, WVt2);
  k2_proj<<<120, 256, 0, stream>>>(xn_bf, W_abcde, b_abcde, proj, a_bf, c_bf, d_bf);
  k3_mid<<<1739, 256, 0, stream>>>(c_bf, W_K, s1bf, d_bf, WVt2, tTt, proj, eT_bf, ecum,
                                   bsum_bf);
  k45_attn<<<dim3(SEQ, 8), 256, 0, stream>>>(a_bf, s1bf, bsum_bf, eT_bf, ecum, ew_bf, Lsum);
  k5b_z<<<dim3(8, 6, 8), 512, 0, stream>>>(ew_bf, tTt, Zpart);
  k6_out<<<96, 256, 0, stream>>>(Zpart, Lsum, W_out, b_out, out);
}

// Round 12
// 219.476 us; speedup vs baseline: 2.6803x; 1.0071x over previous
//
#include <hip/hip_runtime.h>
#include <hip/hip_bf16.h>
#include <cstdint>

#define SEQ 192

typedef float f32x4 __attribute__((ext_vector_type(4)));
typedef float f32x8 __attribute__((ext_vector_type(8)));
typedef __bf16 bf16;
typedef __bf16 bf16x8 __attribute__((ext_vector_type(8)));
typedef __bf16 bf16x4 __attribute__((ext_vector_type(4)));

#define MFMA_BF16(a, b, c) __builtin_amdgcn_mfma_f32_16x16x32_bf16(a, b, c, 0, 0, 0)

__device__ __forceinline__ bf16x8 cvt8(f32x8 v) {
  bf16x8 o;
#pragma unroll
  for (int i = 0; i < 8; i++) o[i] = (bf16)v[i];
  return o;
}

// =================== K1: WVt2 transpose + LayerNorm (R8, proven) ===================
__global__ __launch_bounds__(256) void k1_prep(
    const float* __restrict__ x, const float* __restrict__ ln_w, const float* __restrict__ ln_b,
    const float* __restrict__ WV, bf16* __restrict__ xn_bf, bf16* __restrict__ WVt2) {
  int bid = blockIdx.x, tid = threadIdx.x;
  if (bid < 512) {
    int g = bid & 63, hh = bid >> 6;
    __shared__ float ld[64 * 65];
    int f = tid & 63, r4 = tid >> 6;
#pragma unroll
    for (int it = 0; it < 16; it++) {
      int hp = it * 4 + r4;
      ld[hp * 65 + f] = WV[(((size_t)(hh * 64 + hp) * 64 + g) * 64) + f];
    }
    __syncthreads();
    int hp2 = tid & 63;
#pragma unroll
    for (int it = 0; it < 16; it++) {
      int ff = it * 4 + r4;
      WVt2[(size_t)hh * 262144 + (size_t)(ff * 64 + g) * 64 + hp2] = (bf16)ld[hp2 * 65 + ff];
    }
    return;
  }
  bid -= 512;
  {
    int r = bid;
    const float* xr = x + (size_t)r * 512;
    float v0 = xr[tid], v1 = xr[tid + 256];
    float s = v0 + v1, s2 = v0 * v0 + v1 * v1;
#pragma unroll
    for (int off = 32; off > 0; off >>= 1) {
      s += __shfl_down(s, off);
      s2 += __shfl_down(s2, off);
    }
    __shared__ float redS[4], redS2[4];
    int wave = tid >> 6, lane = tid & 63;
    if (lane == 0) { redS[wave] = s; redS2[wave] = s2; }
    __syncthreads();
    float S = redS[0] + redS[1] + redS[2] + redS[3];
    float S2 = redS2[0] + redS2[1] + redS2[2] + redS2[3];
    float mean = S * (1.0f / 512.0f);
    float var = S2 * (1.0f / 512.0f) - mean * mean;
    float rstd = rsqrtf(var + 1e-5f);
    bf16* xnr = xn_bf + (size_t)r * 512;
    xnr[tid] = (bf16)((v0 - mean) * rstd * ln_w[tid] + ln_b[tid]);
    xnr[tid + 256] = (bf16)((v1 - mean) * rstd * ln_w[tid + 256] + ln_b[tid + 256]);
  }
}

// ---------- LDS-free bf16 GEMM core (bf16 row-major out) ----------
__device__ __forceinline__ void gemm_rm(const bf16* __restrict__ A, const bf16* __restrict__ Bt,
                                        bf16* __restrict__ C1, int N, int K, int nb, int mb,
                                        int tid) {
  int n0 = nb * 64, m0 = mb * 64;
  int wave = tid >> 6, lane = tid & 63;
  int lq = lane >> 4, l16 = lane & 15;
  const bf16* Ap = A + (size_t)(m0 + wave * 16 + l16) * K;
  f32x4 acc[4];
#pragma unroll
  for (int nt = 0; nt < 4; nt++) acc[nt] = (f32x4){0.f, 0.f, 0.f, 0.f};
  for (int k0 = 0; k0 < K; k0 += 32) {
    bf16x8 af = *(const bf16x8*)(Ap + k0 + lq * 8);
#pragma unroll
    for (int nt = 0; nt < 4; nt++) {
      bf16x8 bv = *(const bf16x8*)(Bt + (size_t)(n0 + nt * 16 + l16) * K + k0 + lq * 8);
      acc[nt] = MFMA_BF16(af, bv, acc[nt]);
    }
  }
  int cm = m0 + wave * 16 + lq * 4;
#pragma unroll
  for (int nt = 0; nt < 4; nt++) {
    int n = n0 + nt * 16 + l16;
#pragma unroll
    for (int rg = 0; rg < 4; rg++) C1[(size_t)(cm + rg) * N + n] = (bf16)acc[nt][rg];
  }
}

// =================== K2: proj GEMM + slice epilogue (R8, proven) ===================
__global__ __launch_bounds__(256) void k2_proj(
    const bf16* __restrict__ xn_bf, const float* __restrict__ Wab,
    const float* __restrict__ b_abcde, float* __restrict__ proj, bf16* __restrict__ a_bf,
    bf16* __restrict__ c_bf, bf16* __restrict__ d_bf) {
  int bid = blockIdx.x, tid = threadIdx.x;
  int nb = bid % 40, mb = bid / 40;
  int n0 = nb * 64, m0 = mb * 64;
  int wave = tid >> 6, lane = tid & 63;
  int lq = lane >> 4, l16 = lane & 15;
  const bf16* Ap = xn_bf + (size_t)(m0 + wave * 16 + l16) * 512;
  f32x4 acc[4];
#pragma unroll
  for (int nt = 0; nt < 4; nt++) acc[nt] = (f32x4){0.f, 0.f, 0.f, 0.f};
  for (int k0 = 0; k0 < 512; k0 += 32) {
    bf16x8 af = *(const bf16x8*)(Ap + k0 + lq * 8);
#pragma unroll
    for (int nt = 0; nt < 4; nt++) {
      f32x8 wv = *(const f32x8*)(Wab + (size_t)(n0 + nt * 16 + l16) * 512 + k0 + lq * 8);
      acc[nt] = MFMA_BF16(af, cvt8(wv), acc[nt]);
    }
  }
  int cm = m0 + wave * 16 + lq * 4;
#pragma unroll
  for (int nt = 0; nt < 4; nt++) {
    int n = n0 + nt * 16 + l16;
    int chunk = n >> 9, hcol = (n >> 6) & 7, i = n & 63;
#pragma unroll
    for (int rg = 0; rg < 4; rg++) {
      int m = cm + rg;
      float v = acc[nt][rg] + b_abcde[n];
      proj[(size_t)m * 2560 + n] = v;
      bf16 bv = (bf16)v;
      if (chunk == 0) a_bf[((size_t)hcol * SEQ + m) * 64 + i] = bv;
      else if (chunk == 2) c_bf[(size_t)m * 512 + (n - 1024)] = bv;
      else if (chunk == 3) d_bf[((size_t)hcol * SEQ + m) * 64 + i] = bv;
    }
  }
}

// =================== K3: step1 + t GEMM + eT/ecum + bsum (R8, proven) ===================
__global__ __launch_bounds__(256) void k3_mid(
    const bf16* __restrict__ c_bf, const float* __restrict__ WK, bf16* __restrict__ s1bf,
    const bf16* __restrict__ d_bf, const bf16* __restrict__ WVt2, bf16* __restrict__ tTt,
    const float* __restrict__ proj, bf16* __restrict__ eT_bf, float* __restrict__ ecum,
    bf16* __restrict__ bsum_bf) {
  __shared__ float el[64 * 65];
  int bid = blockIdx.x, tid = threadIdx.x;
  if (bid < 192) {
    int nb = bid % 64, mb = bid / 64;
    int n0 = nb * 64, m0 = mb * 64;
    int wave = tid >> 6, lane = tid & 63;
    int lq = lane >> 4, l16 = lane & 15;
    const bf16* Ap = c_bf + (size_t)(m0 + wave * 16 + l16) * 512;
    f32x4 acc[4];
#pragma unroll
    for (int nt = 0; nt < 4; nt++) acc[nt] = (f32x4){0.f, 0.f, 0.f, 0.f};
    size_t offn[4];
#pragma unroll
    for (int nt = 0; nt < 4; nt++) {
      int n = n0 + nt * 16 + l16;
      offn[nt] = (size_t)(n >> 6) * 4096 + (size_t)(n & 63) * 64;
    }
    for (int k0 = 0; k0 < 512; k0 += 32) {
      bf16x8 af = *(const bf16x8*)(Ap + k0 + lq * 8);
      size_t kb = (size_t)(k0 >> 6) * 262144 + (k0 & 32) + lq * 8;
#pragma unroll
      for (int nt = 0; nt < 4; nt++) {
        f32x8 wv = *(const f32x8*)(WK + kb + offn[nt]);
        acc[nt] = MFMA_BF16(af, cvt8(wv), acc[nt]);
      }
    }
    int cm = m0 + wave * 16 + lq * 4;
#pragma unroll
    for (int nt = 0; nt < 4; nt++) {
      int n = n0 + nt * 16 + l16;
#pragma unroll
      for (int rg = 0; rg < 4; rg++) s1bf[(size_t)(cm + rg) * 4096 + n] = (bf16)acc[nt][rg];
    }
    return;
  }
  bid -= 192;
  if (bid < 1536) {
    int h = bid / 192, rem = bid % 192;
    gemm_rm(d_bf + (size_t)h * 12288, WVt2 + (size_t)h * 262144,
            tTt + (size_t)h * 786432, 4096, 64, rem % 64, rem / 64, tid);
    return;
  }
  bid -= 1536;
  if (bid < 8) {
    int h = bid;
    float carry = 0.f;
    for (int ch = 0; ch < 3; ch++) {
      int pbase = ch * 64;
      if (ch) __syncthreads();
      for (int idx = tid; idx < 4096; idx += 256) {
        int pl = idx >> 6, g = idx & 63;
        el[pl * 65 + g] = proj[(size_t)(pbase + pl) * 2560 + 2048 + h * 64 + g];
      }
      __syncthreads();
      for (int idx = tid; idx < 4096; idx += 256) {
        int g = idx >> 6, ql = idx & 63;
        eT_bf[((size_t)h * 64 + g) * SEQ + pbase + ql] = (bf16)el[ql * 65 + g];
      }
      if (tid < 64) {
        float run = carry;
        for (int pl = 0; pl < 64; pl++) {
          run += el[pl * 65 + tid];
          ecum[(size_t)h * 12288 + (pbase + pl) * 64 + tid] = run;
        }
        carry = run;
      }
      __syncthreads();
    }
    return;
  }
  bid -= 8;
  {
    int j = tid & 63, qg = tid >> 6;
#pragma unroll
    for (int qi = 0; qi < 16; qi++) {
      int q = bid * 64 + qg * 16 + qi;
      float s = 0.f;
#pragma unroll
      for (int hh = 0; hh < 8; hh++) s += proj[(size_t)q * 2560 + 512 + hh * 64 + j];
      bsum_bf[q * 64 + j] = (bf16)s;
    }
  }
}

// =================== K4: step2 GEMM -> s2bf[r][q][i] (R8, proven) ===================
__global__ __launch_bounds__(256) void k4_step2(const bf16* __restrict__ s1bf,
                                                const bf16* __restrict__ bsum_bf,
                                                bf16* __restrict__ s2bf) {
  int bid = blockIdx.x, tid = threadIdx.x;
  int nb = bid % 3, mb = bid / 3;
  int n0 = nb * 64, m0 = mb * 64;
  int wave = tid >> 6, lane = tid & 63;
  int lq = lane >> 4, l16 = lane & 15;
  const bf16* Ap = s1bf + (size_t)(m0 + wave * 16 + l16) * 64;
  f32x4 acc[4];
#pragma unroll
  for (int nt = 0; nt < 4; nt++) acc[nt] = (f32x4){0.f, 0.f, 0.f, 0.f};
#pragma unroll
  for (int k0 = 0; k0 < 64; k0 += 32) {
    bf16x8 af = *(const bf16x8*)(Ap + k0 + lq * 8);
#pragma unroll
    for (int nt = 0; nt < 4; nt++) {
      bf16x8 bv = *(const bf16x8*)(bsum_bf + (size_t)(n0 + nt * 16 + l16) * 64 + k0 + lq * 8);
      acc[nt] = MFMA_BF16(af, bv, acc[nt]);
    }
  }
  int cm = m0 + wave * 16 + lq * 4;
#pragma unroll
  for (int nt = 0; nt < 4; nt++) {
    int n = n0 + nt * 16 + l16;
    int r = cm >> 6, i0 = cm & 63;
    bf16x4 pk = {(bf16)acc[nt][0], (bf16)acc[nt][1], (bf16)acc[nt][2], (bf16)acc[nt][3]};
    *(bf16x4*)(s2bf + (size_t)r * 12288 + (size_t)n * 64 + i0) = pk;
  }
}

// =================== K5: scores+exp+ew(+ecum), single-buffer wch = 15.4 KB LDS ===================
// R7-proven phase-batched body; small LDS -> ~6 blocks/CU residency for latency hiding.
__global__ __launch_bounds__(256, 3) void k5_attn(
    const bf16* __restrict__ a_bf, const bf16* __restrict__ s2bf,
    const bf16* __restrict__ eT_bf, const float* __restrict__ ecum,
    bf16* __restrict__ ew_bf, float* __restrict__ Lsum) {
  int r = blockIdx.x, h = blockIdx.y;
  int tid = threadIdx.x, wave = tid >> 6, lane = tid & 63;
  int lq = lane >> 4, l16 = lane & 15;
  __shared__ __align__(16) bf16 wch[4][3][16 * 40];  // 15.4 KB
  __shared__ float redL[4];
  int pt[3] = {wave, wave + 4, 11 - wave};

  const bf16* ah = a_bf + (size_t)h * 12288;
  const bf16* s2r = s2bf + (size_t)r * 12288;
  const bf16* eh = eT_bf + (size_t)h * 12288;
  const float* ech = ecum + (size_t)h * 12288;

  bf16x8 afr[3][2];
#pragma unroll
  for (int mt = 0; mt < 3; mt++)
#pragma unroll
    for (int kc = 0; kc < 2; kc++)
      afr[mt][kc] = *(const bf16x8*)(ah + (pt[mt] * 16 + l16) * 64 + kc * 32 + lq * 8);

  f32x4 ewacc[3][4];
#pragma unroll
  for (int mt = 0; mt < 3; mt++)
#pragma unroll
    for (int nt = 0; nt < 4; nt++) ewacc[mt][nt] = (f32x4){0.f, 0.f, 0.f, 0.f};
  float lpart = 0.f;

  for (int cc = 0; cc < 6; cc++) {
    if (cc * 32 + 31 <= wave * 16) continue;
    bf16x8 efr[4];
#pragma unroll
    for (int nt = 0; nt < 4; nt++)
      efr[nt] = *(const bf16x8*)(eh + (nt * 16 + l16) * SEQ + cc * 32 + lq * 8);
    bf16x8 bq[2][2];
#pragma unroll
    for (int sub = 0; sub < 2; sub++) {
      int q = cc * 32 + sub * 16 + l16;
      bq[sub][0] = *(const bf16x8*)(s2r + q * 64 + lq * 8);
      bq[sub][1] = *(const bf16x8*)(s2r + q * 64 + 32 + lq * 8);
    }
    // phase 1: all score MFMAs
    f32x4 sacc[3][2];
#pragma unroll
    for (int mt = 0; mt < 3; mt++) {
      if (cc * 32 + 31 <= pt[mt] * 16) continue;
#pragma unroll
      for (int sub = 0; sub < 2; sub++) {
        if (cc * 32 + sub * 16 + 15 <= pt[mt] * 16) continue;
        f32x4 sv = (f32x4){0.f, 0.f, 0.f, 0.f};
        sv = MFMA_BF16(afr[mt][0], bq[sub][0], sv);
        sacc[mt][sub] = MFMA_BF16(afr[mt][1], bq[sub][1], sv);
      }
    }
    // phase 2: all exps + LDS stores (per-wave per-mt buffers; same-wave ordering)
#pragma unroll
    for (int mt = 0; mt < 3; mt++) {
      if (cc * 32 + 31 <= pt[mt] * 16) continue;
      bf16* mybuf = &wch[wave][mt][0];
#pragma unroll
      for (int sub = 0; sub < 2; sub++) {
        if (cc * 32 + sub * 16 + 15 <= pt[mt] * 16) {
#pragma unroll
          for (int rg = 0; rg < 4; rg++) mybuf[(lq * 4 + rg) * 40 + sub * 16 + l16] = (bf16)0.f;
          continue;
        }
        int q = cc * 32 + sub * 16 + l16;
        int p0 = pt[mt] * 16 + lq * 4;
#pragma unroll
        for (int rg = 0; rg < 4; rg++) {
          float wv = (q > p0 + rg) ? __expf(sacc[mt][sub][rg] * 0.015625f) : 0.f;
          lpart += wv;
          mybuf[(lq * 4 + rg) * 40 + sub * 16 + l16] = (bf16)wv;
        }
      }
    }
    // phase 3: all ew MFMAs
#pragma unroll
    for (int mt = 0; mt < 3; mt++) {
      if (cc * 32 + 31 <= pt[mt] * 16) continue;
      bf16x8 wf = *(const bf16x8*)(&wch[wave][mt][l16 * 40 + lq * 8]);
#pragma unroll
      for (int nt = 0; nt < 4; nt++) ewacc[mt][nt] = MFMA_BF16(wf, efr[nt], ewacc[mt][nt]);
    }
  }

  bf16* ewout = ew_bf + ((size_t)h * SEQ + r) * 12288;
#pragma unroll
  for (int mt = 0; mt < 3; mt++)
#pragma unroll
    for (int nt = 0; nt < 4; nt++)
#pragma unroll
      for (int rg = 0; rg < 4; rg++) {
        int pp = pt[mt] * 16 + lq * 4 + rg;
        int g = nt * 16 + l16;
        ewout[pp * 64 + g] = (bf16)(ewacc[mt][nt][rg] + ech[pp * 64 + g]);
      }

#pragma unroll
  for (int off = 32; off > 0; off >>= 1) lpart += __shfl_down(lpart, off);
  if (lane == 0) redL[wave] = lpart;
  __syncthreads();
  if (tid == 0) Lsum[h * SEQ + r] = redL[0] + redL[1] + redL[2] + redL[3];
}

// =================== K5b: Zpart[ks<16] = ew' @ tTt (R10 ph6, proven; 256 thr) ===================
__global__ __launch_bounds__(256) void k5b_z(
    const bf16* __restrict__ ew_bf, const bf16* __restrict__ tTt, float* __restrict__ Zpart) {
  int h = blockIdx.x, mtb = blockIdx.y, ks = blockIdx.z;
  int tid = threadIdx.x, wave = tid >> 6, lane = tid & 63;
  int lq = lane >> 4, l16 = lane & 15;
  __shared__ float zred[4 * 16 * 66];
  const bf16* ewh = ew_bf + ((size_t)h * SEQ + mtb * 32) * 12288;
  const bf16* th = tTt + (size_t)h * 786432;
  f32x4 acc[2][4];
#pragma unroll
  for (int m2 = 0; m2 < 2; m2++)
#pragma unroll
    for (int nt = 0; nt < 4; nt++) acc[m2][nt] = (f32x4){0.f, 0.f, 0.f, 0.f};
#pragma unroll
  for (int jj = 0; jj < 6; jj++) {
    int kc = ks * 24 + wave * 6 + jj;
    int pp = kc >> 1, g0 = (kc & 1) * 32;
    bf16x8 af0 = *(const bf16x8*)(ewh + (size_t)l16 * 12288 + kc * 32 + lq * 8);
    bf16x8 af1 = *(const bf16x8*)(ewh + (size_t)(16 + l16) * 12288 + kc * 32 + lq * 8);
#pragma unroll
    for (int nt = 0; nt < 4; nt++) {
      bf16x8 tf = *(const bf16x8*)(th + (size_t)pp * 4096 + (nt * 16 + l16) * 64 + g0 + lq * 8);
      acc[0][nt] = MFMA_BF16(af0, tf, acc[0][nt]);
      acc[1][nt] = MFMA_BF16(af1, tf, acc[1][nt]);
    }
  }
#pragma unroll
  for (int m2 = 0; m2 < 2; m2++) {
    if (m2) __syncthreads();
#pragma unroll
    for (int nt = 0; nt < 4; nt++)
#pragma unroll
      for (int rg = 0; rg < 4; rg++)
        zred[(wave * 16 + lq * 4 + rg) * 66 + nt * 16 + l16] = acc[m2][nt][rg];
    __syncthreads();
#pragma unroll
    for (int o = 0; o < 4; o++) {
      int idx = o * 256 + tid;  // 1024 outputs [rloc16][f64]
      int rloc = idx >> 6, f = idx & 63;
      float s = zred[rloc * 66 + f] + zred[(16 + rloc) * 66 + f] + zred[(32 + rloc) * 66 + f] +
                zred[(48 + rloc) * 66 + f];
      Zpart[(size_t)ks * 98304 + (size_t)(mtb * 32 + m2 * 16 + rloc) * 512 + h * 64 + f] = s;
    }
  }
}

// =================== K6: z in LDS from 16 Zpart slices (/L) + out GEMM (R10 ph7, proven) ===================
__global__ __launch_bounds__(256) void k6_out(
    const float* __restrict__ Zpart, const float* __restrict__ Lsum,
    const float* __restrict__ Wout, const float* __restrict__ b_out, float* __restrict__ out) {
  int u = blockIdx.x, tid = threadIdx.x;
  int mb = u >> 3, nb = u & 7;
  __shared__ __align__(16) bf16 zt[16 * 520];
  __shared__ float rd[4 * 16 * 68];
  for (int idx = tid; idx < 8192; idx += 256) {
    int m = idx >> 9, cc = idx & 511;
    float s = 0.f;
#pragma unroll
    for (int ks = 0; ks < 16; ks++)
      s += Zpart[(size_t)ks * 98304 + (size_t)(mb * 16 + m) * 512 + cc];
    float L = Lsum[(cc >> 6) * SEQ + mb * 16 + m] + 18528.0f;  // masked mass, w == 1.0f
    zt[m * 520 + cc] = (bf16)(s / L);
  }
  __syncthreads();
  int wave = tid >> 6, lane = tid & 63;
  int lq = lane >> 4, l16 = lane & 15;
  f32x4 acc[4];
#pragma unroll
  for (int nt = 0; nt < 4; nt++) acc[nt] = (f32x4){0.f, 0.f, 0.f, 0.f};
#pragma unroll
  for (int kc = 0; kc < 4; kc++) {
    int k0 = wave * 128 + kc * 32;
    bf16x8 af = *(const bf16x8*)(zt + l16 * 520 + k0 + lq * 8);
#pragma unroll
    for (int nt = 0; nt < 4; nt++) {
      f32x8 wv = *(const f32x8*)(Wout + (size_t)(nb * 64 + nt * 16 + l16) * 512 + k0 + lq * 8);
      acc[nt] = MFMA_BF16(af, cvt8(wv), acc[nt]);
    }
  }
#pragma unroll
  for (int nt = 0; nt < 4; nt++)
#pragma unroll
    for (int rg = 0; rg < 4; rg++)
      rd[(wave * 16 + lq * 4 + rg) * 68 + nt * 16 + l16] = acc[nt][rg];
  __syncthreads();
#pragma unroll
  for (int o = 0; o < 4; o++) {
    int idx = o * 256 + tid;
    int rloc = idx >> 6, f = idx & 63;
    float s = rd[rloc * 68 + f] + rd[(16 + rloc) * 68 + f] + rd[(32 + rloc) * 68 + f] +
              rd[(48 + rloc) * 68 + f];
    out[(size_t)(mb * 16 + rloc) * 512 + nb * 64 + f] = s + b_out[nb * 64 + f];
  }
}

// =================== workspace layout (f32 units) ===================
static const size_t OFF_PROJ = 0;          // f32 491520
static const size_t OFF_ECUM = 491520;     // f32 98304
static const size_t OFF_XN = 589824;       // bf16 -> 49152
static const size_t OFF_LSUM = 638976;     // f32 1536
static const size_t OFF_ZPART = 640512;    // f32 1572864 (16 slices)
static const size_t OFF_WVT = 2213376;     // bf16 -> 1048576
static const size_t OFF_A = 3261952;       // bf16 -> 49152
static const size_t OFF_C = 3311104;       // 49152
static const size_t OFF_D = 3360256;       // 49152
static const size_t OFF_ET = 3409408;      // 49152
static const size_t OFF_BSUM = 3458560;    // 6144
static const size_t OFF_S1 = 3464704;      // bf16 -> 393216
static const size_t OFF_TT = 5037568;      // bf16 -> 3145728
static const size_t OFF_EW = 8183296;      // bf16 -> 9437184
static const size_t OFF_S2 = 17620480;     // bf16 2359296 -> 1179648
// TOTAL = 18800128 f32 = 75.2 MB

extern "C" void kernel_launch(void* const* d_in, const int* in_sizes, int n_in,
                              void* d_out, int out_size, void* d_ws, size_t ws_size,
                              hipStream_t stream) {
  (void)in_sizes; (void)n_in; (void)out_size; (void)ws_size;
  const float* x = (const float*)d_in[0];
  const float* ln_w = (const float*)d_in[1];
  const float* ln_b = (const float*)d_in[2];
  const float* W_abcde = (const float*)d_in[3];
  const float* b_abcde = (const float*)d_in[4];
  const float* W_K = (const float*)d_in[5];
  const float* W_V = (const float*)d_in[6];
  const float* W_out = (const float*)d_in[7];
  const float* b_out = (const float*)d_in[8];
  float* out = (float*)d_out;
  float* ws = (float*)d_ws;

  float* proj = ws + OFF_PROJ;
  float* ecum = ws + OFF_ECUM;
  bf16* xn_bf = (bf16*)(ws + OFF_XN);
  float* Lsum = ws + OFF_LSUM;
  float* Zpart = ws + OFF_ZPART;
  bf16* WVt2 = (bf16*)(ws + OFF_WVT);
  bf16* a_bf = (bf16*)(ws + OFF_A);
  bf16* c_bf = (bf16*)(ws + OFF_C);
  bf16* d_bf = (bf16*)(ws + OFF_D);
  bf16* eT_bf = (bf16*)(ws + OFF_ET);
  bf16* bsum_bf = (bf16*)(ws + OFF_BSUM);
  bf16* s1bf = (bf16*)(ws + OFF_S1);
  bf16* tTt = (bf16*)(ws + OFF_TT);
  bf16* ew_bf = (bf16*)(ws + OFF_EW);
  bf16* s2bf = (bf16*)(ws + OFF_S2);

  k1_prep<<<704, 256, 0, stream>>>(x, ln_w, ln_b, W_V, xn_bf, WVt2);
  k2_proj<<<120, 256, 0, stream>>>(xn_bf, W_abcde, b_abcde, proj, a_bf, c_bf, d_bf);
  k3_mid<<<1739, 256, 0, stream>>>(c_bf, W_K, s1bf, d_bf, WVt2, tTt, proj, eT_bf, ecum,
                                   bsum_bf);
  k4_step2<<<576, 256, 0, stream>>>(s1bf, bsum_bf, s2bf);
  k5_attn<<<dim3(SEQ, 8), 256, 0, stream>>>(a_bf, s2bf, eT_bf, ecum, ew_bf, Lsum);
  k5b_z<<<dim3(8, 6, 16), 256, 0, stream>>>(ew_bf, tTt, Zpart);
  k6_out<<<96, 256, 0, stream>>>(Zpart, Lsum, W_out, b_out, out);
}